// Round 7
// baseline (351.604 us; speedup 1.0000x reference)
//
#include <hip/hip_runtime.h>

#define LRELU_SLOPE 0.2f
#define TM 16

__device__ __forceinline__ float lrelu(float v) {
    return v > 0.f ? v : LRELU_SLOPE * v;
}
// bf16 (as ushort) -> fp32, exact
__device__ __forceinline__ float b2f(unsigned short u) {
    union { unsigned u; float f; } c;
    c.u = ((unsigned)u) << 16;
    return c.f;
}
__device__ __forceinline__ float u2f_lo(unsigned u) {
    union { unsigned u; float f; } c;
    c.u = u << 16;
    return c.f;
}
__device__ __forceinline__ float u2f_hi(unsigned u) {
    union { unsigned u; float f; } c;
    c.u = u & 0xffff0000u;
    return c.f;
}
// fp32 -> bf16 (round to nearest even)
__device__ __forceinline__ unsigned short f2b(float f) {
    union { float f; unsigned u; } c;
    c.f = f;
    unsigned r = c.u + 0x7fffu + ((c.u >> 16) & 1u);
    return (unsigned short)(r >> 16);
}

// generic loads; dtype fixed per template instantiation
template <bool BF16>
__device__ __forceinline__ float ldx(const void* p, size_t i) {
    if (BF16) return b2f(((const unsigned short*)p)[i]);
    return ((const float*)p)[i];
}
template <bool BF16>
__device__ __forceinline__ float4 ldx4(const void* p, size_t i) {
    if (BF16) {
        uint2 u = *(const uint2*)((const unsigned short*)p + i);
        return make_float4(u2f_lo(u.x), u2f_hi(u.x), u2f_lo(u.y), u2f_hi(u.y));
    }
    return *(const float4*)((const float*)p + i);
}

// ---------------------------------------------------------------------------
// K-1: detect (a) edge index width, (b) float tensor dtype.
// flags[0]=1 if edges int64 (16 high u32 words all zero).
// flags[1]=1 if x bf16 (bf16 N(0,1) never exceeds |8|; fp32-as-ushort halves
// decode as bf16 with |v|>64 a large fraction of the time; 2048 samples).
// Session evidence: inputs are fp32 (r0 absmax=max|ref|, r2 NaN under bf16
// reads, r5 clean fp32 run) -- the bf16 path is kept as a cheap safety net.
// ---------------------------------------------------------------------------
__global__ void k_detect(const unsigned int* __restrict__ eraw,
                         const unsigned short* __restrict__ x16,
                         int* __restrict__ flags) {
    const int lane = threadIdx.x & 63;
    int e64 = 1;
    if (lane < 16) e64 = (eraw[2 * lane + 1] == 0u) ? 1 : 0;
    int big = 0;
    for (int k = lane; k < 2048; k += 64) {
        float v = b2f(x16[k]);
        if (fabsf(v) > 64.f) ++big;
    }
#pragma unroll
    for (int d = 1; d < 64; d <<= 1) {
        e64 = min(e64, __shfl_xor(e64, d));
        big += __shfl_xor(big, d);
    }
    if (lane == 0) {
        flags[0] = e64;
        flags[1] = (big < 8) ? 1 : 0;
    }
}

__device__ __forceinline__ int edge_at(const unsigned int* raw, int f,
                                       size_t idx) {
    return f ? (int)raw[2 * idx] : (int)raw[idx];
}

// ---------------------------------------------------------------------------
// K1: xl = x@W_l+b_l (-> bf16), xr = x@W_r+b_r (-> fp32). (Nx64)@(64x256).
// 16 nodes per 256-thread block; fp32 x-tile in LDS; thread j owns column j.
// ---------------------------------------------------------------------------
template <bool BF16>
__global__ __launch_bounds__(256) void k_proj(
    const void* __restrict__ x, const void* __restrict__ Wl,
    const void* __restrict__ bl, const void* __restrict__ Wr,
    const void* __restrict__ br, unsigned short* __restrict__ xl,
    float* __restrict__ xr, int N, const int* __restrict__ flags) {
    if (flags[1] != (BF16 ? 1 : 0)) return;
    __shared__ float xs[64][TM + 4];
    const int tid = threadIdx.x;
    const int base = blockIdx.x * TM;
    for (int t = tid; t < TM * 64; t += 256) {
        int m = t >> 6, k = t & 63;
        int n = base + m;
        xs[k][m] = (n < N) ? ldx<BF16>(x, (size_t)n * 64 + k) : 0.f;
    }
    __syncthreads();
    const int j = tid;  // output column 0..255
    float accl[TM], accr[TM];
    const float blj = ldx<BF16>(bl, j);
    const float brj = ldx<BF16>(br, j);
#pragma unroll
    for (int m = 0; m < TM; ++m) { accl[m] = blj; accr[m] = brj; }
    for (int k = 0; k < 64; ++k) {
        float wl = ldx<BF16>(Wl, (size_t)k * 256 + j);
        float wr = ldx<BF16>(Wr, (size_t)k * 256 + j);
        const float4* xrow = (const float4*)(&xs[k][0]);
#pragma unroll
        for (int mm = 0; mm < TM / 4; ++mm) {
            float4 xv = xrow[mm];
            accl[4 * mm + 0] = fmaf(xv.x, wl, accl[4 * mm + 0]);
            accl[4 * mm + 1] = fmaf(xv.y, wl, accl[4 * mm + 1]);
            accl[4 * mm + 2] = fmaf(xv.z, wl, accl[4 * mm + 2]);
            accl[4 * mm + 3] = fmaf(xv.w, wl, accl[4 * mm + 3]);
            accr[4 * mm + 0] = fmaf(xv.x, wr, accr[4 * mm + 0]);
            accr[4 * mm + 1] = fmaf(xv.y, wr, accr[4 * mm + 1]);
            accr[4 * mm + 2] = fmaf(xv.z, wr, accr[4 * mm + 2]);
            accr[4 * mm + 3] = fmaf(xv.w, wr, accr[4 * mm + 3]);
        }
    }
#pragma unroll
    for (int m = 0; m < TM; ++m) {
        int n = base + m;
        if (n < N) {
            xl[(size_t)n * 256 + j] = f2b(accl[m]);
            xr[(size_t)n * 256 + j] = accr[m];
        }
    }
}

// ---------------------------------------------------------------------------
// CSR build: histogram -> 3-phase exclusive scan -> scatter
// ---------------------------------------------------------------------------
__global__ void k_hist(const unsigned int* __restrict__ raw,
                       const int* __restrict__ flags, int* __restrict__ deg,
                       int E, int Etot, int N) {
    int e = blockIdx.x * 256 + threadIdx.x;
    if (e >= Etot) return;
    int f = flags[0];
    int d = (e < E) ? edge_at(raw, f, (size_t)E + e) : (e - E);
    if ((unsigned)d >= (unsigned)N) d = 0;  // defensive clamp
    atomicAdd(&deg[d], 1);
}

__global__ void k_scanA(const int* __restrict__ deg, int* __restrict__ bsum,
                        int N) {
    __shared__ int s[256];
    int t = threadIdx.x;
    int i = blockIdx.x * 256 + t;
    s[t] = (i < N) ? deg[i] : 0;
    __syncthreads();
    for (int d = 128; d > 0; d >>= 1) {
        if (t < d) s[t] += s[t + d];
        __syncthreads();
    }
    if (t == 0) bsum[blockIdx.x] = s[0];
}

// single block scans up to 256 block sums (N <= 65536)
__global__ void k_scanB(int* __restrict__ bsum, int* __restrict__ row_start,
                        int NB, int Etot, int N) {
    __shared__ int s[256];
    int t = threadIdx.x;
    int v = (t < NB) ? bsum[t] : 0;
    s[t] = v;
    __syncthreads();
    for (int d = 1; d < 256; d <<= 1) {
        int add = (t >= d) ? s[t - d] : 0;
        __syncthreads();
        s[t] += add;
        __syncthreads();
    }
    if (t < NB) bsum[t] = s[t] - v;  // exclusive
    if (t == 0) row_start[N] = Etot;
}

__global__ void k_scanC(const int* __restrict__ deg,
                        const int* __restrict__ bsum,
                        int* __restrict__ row_start, int N) {
    __shared__ int s[256];
    int t = threadIdx.x;
    int i = blockIdx.x * 256 + t;
    int v = (i < N) ? deg[i] : 0;
    s[t] = v;
    __syncthreads();
    for (int d = 1; d < 256; d <<= 1) {
        int add = (t >= d) ? s[t - d] : 0;
        __syncthreads();
        s[t] += add;
        __syncthreads();
    }
    if (i < N) row_start[i] = s[t] - v + bsum[blockIdx.x];
}

__global__ void k_scatter(const unsigned int* __restrict__ raw,
                          const int* __restrict__ flags,
                          const int* __restrict__ row_start,
                          int* __restrict__ cursor, int* __restrict__ csr_src,
                          int E, int Etot, int N) {
    int e = blockIdx.x * 256 + threadIdx.x;
    if (e >= Etot) return;
    int f = flags[0];
    int s, d;
    if (e < E) {
        s = edge_at(raw, f, (size_t)e);
        d = edge_at(raw, f, (size_t)E + e);
    } else {
        s = d = e - E;
    }
    if ((unsigned)s >= (unsigned)N) s = 0;  // defensive clamp
    if ((unsigned)d >= (unsigned)N) d = 0;
    int pos = atomicAdd(&cursor[d], 1);
    int slot = row_start[d] + pos;
    if ((unsigned)slot < (unsigned)Etot) csr_src[slot] = s;
}

// ---------------------------------------------------------------------------
// K3: per-node softmax-aggregate. One wave per node.
// lane -> (head = lane>>4, quad = lane&15): lane owns 4 channels of one head.
// Per edge: 8B bf16 gather of xl[src], leaky+dot, 16-lane butterfly reduce,
// clamped exp (softmax shift-invariant; true scores O(1)), den/acc in regs.
// Output dtype matches input dtype: fp32 path writes float4.
// ---------------------------------------------------------------------------
template <bool BF16>
__global__ __launch_bounds__(256) void k_aggregate(
    const unsigned short* __restrict__ xl, const float* __restrict__ xr,
    const void* __restrict__ att, const void* __restrict__ bias,
    const int* __restrict__ row_start, const int* __restrict__ csr_src,
    void* __restrict__ out, int N, const int* __restrict__ flags) {
    if (flags[1] != (BF16 ? 1 : 0)) return;
    const int wave = threadIdx.x >> 6;
    const int lane = threadIdx.x & 63;
    const int i = blockIdx.x * 4 + wave;
    if (i >= N) return;
    const int q = lane & 15;
    const int off = (lane >> 4) * 64 + q * 4;  // element offset in 256-row

    const float4 xr4 = *(const float4*)(xr + (size_t)i * 256 + off);
    const float4 a4 = ldx4<BF16>(att, off);
    float4 acc = make_float4(0.f, 0.f, 0.f, 0.f);
    float den = 0.f;
    int idx = row_start[i];
    const int end = row_start[i + 1];
    int src = (idx < end) ? csr_src[idx] : 0;
    if ((unsigned)src >= (unsigned)N) src = 0;
    uint2 xc = *(const uint2*)(xl + (size_t)src * 256 + off);
    while (idx < end) {
        uint2 cu = xc;
        ++idx;
        if (idx < end) {  // prefetch next edge's row
            int s2 = csr_src[idx];
            if ((unsigned)s2 >= (unsigned)N) s2 = 0;
            xc = *(const uint2*)(xl + (size_t)s2 * 256 + off);
        }
        float c0 = u2f_lo(cu.x), c1 = u2f_hi(cu.x);
        float c2 = u2f_lo(cu.y), c3 = u2f_hi(cu.y);
        float t = a4.x * lrelu(c0 + xr4.x);
        t = fmaf(a4.y, lrelu(c1 + xr4.y), t);
        t = fmaf(a4.z, lrelu(c2 + xr4.z), t);
        t = fmaf(a4.w, lrelu(c3 + xr4.w), t);
        t += __shfl_xor(t, 1);
        t += __shfl_xor(t, 2);
        t += __shfl_xor(t, 4);
        t += __shfl_xor(t, 8);  // full 64-chan dot for this head
        t = fminf(fmaxf(t, -30.f), 30.f);  // true scores O(1); guard junk
        float w = __expf(t);
        den += w;
        acc.x = fmaf(w, c0, acc.x);
        acc.y = fmaf(w, c1, acc.y);
        acc.z = fmaf(w, c2, acc.z);
        acc.w = fmaf(w, c3, acc.w);
    }
    const float inv = 1.f / fmaxf(den, 1e-30f);
    float r0 = acc.x * inv, r1 = acc.y * inv, r2 = acc.z * inv, r3 = acc.w * inv;
    // sum over the 4 heads (lanes q, q+16, q+32, q+48)
    r0 += __shfl_xor(r0, 16); r0 += __shfl_xor(r0, 32);
    r1 += __shfl_xor(r1, 16); r1 += __shfl_xor(r1, 32);
    r2 += __shfl_xor(r2, 16); r2 += __shfl_xor(r2, 32);
    r3 += __shfl_xor(r3, 16); r3 += __shfl_xor(r3, 32);
    if (lane < 16) {
        float4 b4 = ldx4<BF16>(bias, q * 4);
        float o0 = b4.x + 0.25f * r0;
        float o1 = b4.y + 0.25f * r1;
        float o2 = b4.z + 0.25f * r2;
        float o3 = b4.w + 0.25f * r3;
        if (BF16) {
            uint2 ov;
            ov.x = (unsigned)f2b(o0) | ((unsigned)f2b(o1) << 16);
            ov.y = (unsigned)f2b(o2) | ((unsigned)f2b(o3) << 16);
            *(uint2*)((unsigned short*)out + (size_t)i * 64 + q * 4) = ov;
        } else {
            *(float4*)((float*)out + (size_t)i * 64 + q * 4) =
                make_float4(o0, o1, o2, o3);
        }
    }
}

// ---------------------------------------------------------------------------
extern "C" void kernel_launch(void* const* d_in, const int* in_sizes, int n_in,
                              void* d_out, int out_size, void* d_ws,
                              size_t ws_size, hipStream_t stream) {
    const void* x    = d_in[0];
    const void* Wl   = d_in[1];
    const void* bl   = d_in[2];
    const void* Wr   = d_in[3];
    const void* br   = d_in[4];
    const void* att  = d_in[5];
    const void* bias = d_in[6];
    const unsigned int* edges_raw = (const unsigned int*)d_in[7];

    const int N = in_sizes[0] / 64;
    const int E = in_sizes[7] / 2;
    const int Etot = E + N;

    // workspace layout (~81 MB total; <= 87 MB evidenced safe in r2/r5)
    char* p = (char*)d_ws;
    size_t off = 0;
    auto carve = [&](size_t bytes) -> char* {
        char* r = p + off;
        off = (off + bytes + 255) & ~(size_t)255;
        return r;
    };
    unsigned short* xl = (unsigned short*)carve((size_t)N * 256 * 2);  // 25.6 MB
    float* xr      = (float*)carve((size_t)N * 256 * 4);               // 51.2 MB
    int* csr_src   = (int*)carve((size_t)Etot * 4);                    // 3.4 MB
    int* row_start = (int*)carve((size_t)(N + 1) * 4);
    int* deg       = (int*)carve((size_t)N * 4);
    int* cursor    = (int*)carve((size_t)N * 4);
    int* bsum      = (int*)carve(1024 * 4);
    int* flags     = (int*)carve(256);

    hipMemsetAsync(deg, 0, (size_t)N * 4, stream);
    hipMemsetAsync(cursor, 0, (size_t)N * 4, stream);

    k_detect<<<1, 64, 0, stream>>>(edges_raw, (const unsigned short*)x, flags);
    const int PB = (N + TM - 1) / TM;
    k_proj<false><<<PB, 256, 0, stream>>>(x, Wl, bl, Wr, br, xl, xr, N, flags);
    k_proj<true><<<PB, 256, 0, stream>>>(x, Wl, bl, Wr, br, xl, xr, N, flags);
    k_hist<<<(Etot + 255) / 256, 256, 0, stream>>>(edges_raw, flags, deg, E,
                                                   Etot, N);
    const int NB = (N + 255) / 256;  // 196 <= 256: single-block scanB OK
    k_scanA<<<NB, 256, 0, stream>>>(deg, bsum, N);
    k_scanB<<<1, 256, 0, stream>>>(bsum, row_start, NB, Etot, N);
    k_scanC<<<NB, 256, 0, stream>>>(deg, bsum, row_start, N);
    k_scatter<<<(Etot + 255) / 256, 256, 0, stream>>>(edges_raw, flags,
                                                      row_start, cursor,
                                                      csr_src, E, Etot, N);
    const int AB = (N + 3) / 4;
    k_aggregate<false><<<AB, 256, 0, stream>>>(xl, xr, att, bias, row_start,
                                               csr_src, d_out, N, flags);
    k_aggregate<true><<<AB, 256, 0, stream>>>(xl, xr, att, bias, row_start,
                                              csr_src, d_out, N, flags);
}

// Round 8
// 303.947 us; speedup vs baseline: 1.1568x; 1.1568x over previous
//
#include <hip/hip_runtime.h>

#define TM 16

// bf16 helpers (xl is staged in bf16 to halve gather traffic)
__device__ __forceinline__ float u2f_lo(unsigned u) {
    union { unsigned u; float f; } c;
    c.u = u << 16;
    return c.f;
}
__device__ __forceinline__ float u2f_hi(unsigned u) {
    union { unsigned u; float f; } c;
    c.u = u & 0xffff0000u;
    return c.f;
}
// fp32 -> bf16 (round to nearest even)
__device__ __forceinline__ unsigned short f2b(float f) {
    union { float f; unsigned u; } c;
    c.f = f;
    unsigned r = c.u + 0x7fffu + ((c.u >> 16) & 1u);
    return (unsigned short)(r >> 16);
}

// ---------------------------------------------------------------------------
// K0: detect edge index width. flags[0]=1 if int64 (16 high words all zero).
// (Float dtype is fp32 — confirmed on-device r7: fp32 path executed, passed.)
// ---------------------------------------------------------------------------
__global__ void k_detect(const unsigned int* __restrict__ eraw,
                         int* __restrict__ flags) {
    if (threadIdx.x == 0) {
        int e64 = 1;
#pragma unroll
        for (int k = 0; k < 16; ++k) e64 = e64 && (eraw[2 * k + 1] == 0u);
        flags[0] = e64;
    }
}

__device__ __forceinline__ int edge_at(const unsigned int* raw, int f,
                                       size_t idx) {
    return f ? (int)raw[2 * idx] : (int)raw[idx];
}

// ---------------------------------------------------------------------------
// K1: xl = x@W_l+b_l (-> bf16), xr = x@W_r+b_r (-> fp32). (Nx64)@(64x256).
// 16 nodes per 256-thread block; x-tile in LDS; thread j owns column j.
// ---------------------------------------------------------------------------
__global__ __launch_bounds__(256) void k_proj(
    const float* __restrict__ x, const float* __restrict__ Wl,
    const float* __restrict__ bl, const float* __restrict__ Wr,
    const float* __restrict__ br, unsigned short* __restrict__ xl,
    float* __restrict__ xr, int N) {
    __shared__ float xs[64][TM + 4];
    const int tid = threadIdx.x;
    const int base = blockIdx.x * TM;
    for (int t = tid; t < TM * 64; t += 256) {
        int m = t >> 6, k = t & 63;
        int n = base + m;
        xs[k][m] = (n < N) ? x[(size_t)n * 64 + k] : 0.f;
    }
    __syncthreads();
    const int j = tid;  // output column 0..255
    float accl[TM], accr[TM];
    const float blj = bl[j], brj = br[j];
#pragma unroll
    for (int m = 0; m < TM; ++m) { accl[m] = blj; accr[m] = brj; }
    for (int k = 0; k < 64; ++k) {
        float wl = Wl[(size_t)k * 256 + j];
        float wr = Wr[(size_t)k * 256 + j];
        const float4* xrow = (const float4*)(&xs[k][0]);
#pragma unroll
        for (int mm = 0; mm < TM / 4; ++mm) {
            float4 xv = xrow[mm];
            accl[4 * mm + 0] = fmaf(xv.x, wl, accl[4 * mm + 0]);
            accl[4 * mm + 1] = fmaf(xv.y, wl, accl[4 * mm + 1]);
            accl[4 * mm + 2] = fmaf(xv.z, wl, accl[4 * mm + 2]);
            accl[4 * mm + 3] = fmaf(xv.w, wl, accl[4 * mm + 3]);
            accr[4 * mm + 0] = fmaf(xv.x, wr, accr[4 * mm + 0]);
            accr[4 * mm + 1] = fmaf(xv.y, wr, accr[4 * mm + 1]);
            accr[4 * mm + 2] = fmaf(xv.z, wr, accr[4 * mm + 2]);
            accr[4 * mm + 3] = fmaf(xv.w, wr, accr[4 * mm + 3]);
        }
    }
#pragma unroll
    for (int m = 0; m < TM; ++m) {
        int n = base + m;
        if (n < N) {
            xl[(size_t)n * 256 + j] = f2b(accl[m]);
            xr[(size_t)n * 256 + j] = accr[m];
        }
    }
}

// ---------------------------------------------------------------------------
// CSR build: histogram -> 3-phase exclusive scan -> scatter
// ---------------------------------------------------------------------------
__global__ void k_hist(const unsigned int* __restrict__ raw,
                       const int* __restrict__ flags, int* __restrict__ deg,
                       int E, int Etot, int N) {
    int e = blockIdx.x * 256 + threadIdx.x;
    if (e >= Etot) return;
    int f = flags[0];
    int d = (e < E) ? edge_at(raw, f, (size_t)E + e) : (e - E);
    if ((unsigned)d >= (unsigned)N) d = 0;  // defensive clamp
    atomicAdd(&deg[d], 1);
}

__global__ void k_scanA(const int* __restrict__ deg, int* __restrict__ bsum,
                        int N) {
    __shared__ int s[256];
    int t = threadIdx.x;
    int i = blockIdx.x * 256 + t;
    s[t] = (i < N) ? deg[i] : 0;
    __syncthreads();
    for (int d = 128; d > 0; d >>= 1) {
        if (t < d) s[t] += s[t + d];
        __syncthreads();
    }
    if (t == 0) bsum[blockIdx.x] = s[0];
}

// single block scans up to 256 block sums (N <= 65536)
__global__ void k_scanB(int* __restrict__ bsum, int* __restrict__ row_start,
                        int NB, int Etot, int N) {
    __shared__ int s[256];
    int t = threadIdx.x;
    int v = (t < NB) ? bsum[t] : 0;
    s[t] = v;
    __syncthreads();
    for (int d = 1; d < 256; d <<= 1) {
        int add = (t >= d) ? s[t - d] : 0;
        __syncthreads();
        s[t] += add;
        __syncthreads();
    }
    if (t < NB) bsum[t] = s[t] - v;  // exclusive
    if (t == 0) row_start[N] = Etot;
}

__global__ void k_scanC(const int* __restrict__ deg,
                        const int* __restrict__ bsum,
                        int* __restrict__ row_start, int N) {
    __shared__ int s[256];
    int t = threadIdx.x;
    int i = blockIdx.x * 256 + t;
    int v = (i < N) ? deg[i] : 0;
    s[t] = v;
    __syncthreads();
    for (int d = 1; d < 256; d <<= 1) {
        int add = (t >= d) ? s[t - d] : 0;
        __syncthreads();
        s[t] += add;
        __syncthreads();
    }
    if (i < N) row_start[i] = s[t] - v + bsum[blockIdx.x];
}

__global__ void k_scatter(const unsigned int* __restrict__ raw,
                          const int* __restrict__ flags,
                          const int* __restrict__ row_start,
                          int* __restrict__ cursor, int* __restrict__ csr_src,
                          int E, int Etot, int N) {
    int e = blockIdx.x * 256 + threadIdx.x;
    if (e >= Etot) return;
    int f = flags[0];
    int s, d;
    if (e < E) {
        s = edge_at(raw, f, (size_t)e);
        d = edge_at(raw, f, (size_t)E + e);
    } else {
        s = d = e - E;
    }
    if ((unsigned)s >= (unsigned)N) s = 0;  // defensive clamp
    if ((unsigned)d >= (unsigned)N) d = 0;
    int pos = atomicAdd(&cursor[d], 1);
    int slot = row_start[d] + pos;
    if ((unsigned)slot < (unsigned)Etot) csr_src[slot] = s;
    // note: positions are a permutation of [0,Etot) -> every slot written,
    // every value < N. k_aggregate relies on this (no interior clamps).
}

// ---------------------------------------------------------------------------
// K3: per-node softmax-aggregate. One wave per node.
// lane -> (head = lane>>4, quad = lane&15): lane owns 4 channels of one head.
// r7 profile: latency-bound (VALUBusy 57%, hbm 22%, prefetch depth 1).
// Now software-pipelined: csr-index ring fetched 2P ahead, gather ring P=4
// ahead, both register-resident and branch-free via min(.,last) clamping
// (tail re-gathers the last row; <=P redundant L1-hit loads per node).
// ---------------------------------------------------------------------------
__global__ __launch_bounds__(256) void k_aggregate(
    const unsigned short* __restrict__ xl, const float* __restrict__ xr,
    const float* __restrict__ att, const float* __restrict__ bias,
    const int* __restrict__ row_start, const int* __restrict__ csr_src,
    float* __restrict__ out, int N) {
    const int wave = threadIdx.x >> 6;
    const int lane = threadIdx.x & 63;
    const int i = blockIdx.x * 4 + wave;
    if (i >= N) return;
    const int q = lane & 15;
    const int off = (lane >> 4) * 64 + q * 4;  // element offset in 256-row

    const float4 xr4 = *(const float4*)(xr + (size_t)i * 256 + off);
    const float4 a4 = *(const float4*)(att + off);
    float4 acc = make_float4(0.f, 0.f, 0.f, 0.f);
    float den = 0.f;
    const int beg = row_start[i];
    const int end = row_start[i + 1];  // deg >= 1 (self loop)
    const int last = end - 1;
    const unsigned short* xlo = xl + off;  // lane-constant base

    constexpr int P = 4;
    uint2 buf[P];   // gathered rows for edges e .. e+P-1
    int sreg[P];    // csr values for edges e+P .. e+2P-1
#pragma unroll
    for (int k = 0; k < P; ++k) {
        int s = csr_src[min(beg + k, last)];
        buf[k] = *(const uint2*)(xlo + (size_t)s * 256);
    }
#pragma unroll
    for (int k = 0; k < P; ++k) sreg[k] = csr_src[min(beg + P + k, last)];

    for (int e = beg; e < end; ++e) {
        uint2 cu = buf[0];
#pragma unroll
        for (int k = 0; k < P - 1; ++k) buf[k] = buf[k + 1];
        buf[P - 1] = *(const uint2*)(xlo + (size_t)sreg[0] * 256);
#pragma unroll
        for (int k = 0; k < P - 1; ++k) sreg[k] = sreg[k + 1];
        sreg[P - 1] = csr_src[min(e + 2 * P, last)];

        float c0 = u2f_lo(cu.x), c1 = u2f_hi(cu.x);
        float c2 = u2f_lo(cu.y), c3 = u2f_hi(cu.y);
        float v0 = c0 + xr4.x, v1 = c1 + xr4.y;
        float v2 = c2 + xr4.z, v3 = c3 + xr4.w;
        // lrelu(v) = max(v, 0.2v): 2 ops, no compare/select
        v0 = fmaxf(v0, 0.2f * v0);
        v1 = fmaxf(v1, 0.2f * v1);
        v2 = fmaxf(v2, 0.2f * v2);
        v3 = fmaxf(v3, 0.2f * v3);
        float t = a4.x * v0;
        t = fmaf(a4.y, v1, t);
        t = fmaf(a4.z, v2, t);
        t = fmaf(a4.w, v3, t);
        t += __shfl_xor(t, 1);
        t += __shfl_xor(t, 2);
        t += __shfl_xor(t, 4);
        t += __shfl_xor(t, 8);  // full 64-chan dot for this head
        float w = __expf(fminf(t, 60.f));  // true scores O(1); overflow guard
        den += w;
        acc.x = fmaf(w, c0, acc.x);
        acc.y = fmaf(w, c1, acc.y);
        acc.z = fmaf(w, c2, acc.z);
        acc.w = fmaf(w, c3, acc.w);
    }
    const float inv = 1.f / den;
    float r0 = acc.x * inv, r1 = acc.y * inv, r2 = acc.z * inv, r3 = acc.w * inv;
    // sum over the 4 heads (lanes q, q+16, q+32, q+48)
    r0 += __shfl_xor(r0, 16); r0 += __shfl_xor(r0, 32);
    r1 += __shfl_xor(r1, 16); r1 += __shfl_xor(r1, 32);
    r2 += __shfl_xor(r2, 16); r2 += __shfl_xor(r2, 32);
    r3 += __shfl_xor(r3, 16); r3 += __shfl_xor(r3, 32);
    if (lane < 16) {
        const float4 b4 = *(const float4*)(bias + q * 4);
        *(float4*)(out + (size_t)i * 64 + q * 4) =
            make_float4(b4.x + 0.25f * r0, b4.y + 0.25f * r1,
                        b4.z + 0.25f * r2, b4.w + 0.25f * r3);
    }
}

// ---------------------------------------------------------------------------
extern "C" void kernel_launch(void* const* d_in, const int* in_sizes, int n_in,
                              void* d_out, int out_size, void* d_ws,
                              size_t ws_size, hipStream_t stream) {
    const float* x    = (const float*)d_in[0];
    const float* Wl   = (const float*)d_in[1];
    const float* bl   = (const float*)d_in[2];
    const float* Wr   = (const float*)d_in[3];
    const float* br   = (const float*)d_in[4];
    const float* att  = (const float*)d_in[5];
    const float* bias = (const float*)d_in[6];
    const unsigned int* edges_raw = (const unsigned int*)d_in[7];

    const int N = in_sizes[0] / 64;
    const int E = in_sizes[7] / 2;
    const int Etot = E + N;

    // workspace layout (~81 MB; evidenced safe r2/r5/r7)
    char* p = (char*)d_ws;
    size_t off = 0;
    auto carve = [&](size_t bytes) -> char* {
        char* r = p + off;
        off = (off + bytes + 255) & ~(size_t)255;
        return r;
    };
    unsigned short* xl = (unsigned short*)carve((size_t)N * 256 * 2);  // 25.6 MB
    float* xr      = (float*)carve((size_t)N * 256 * 4);               // 51.2 MB
    int* csr_src   = (int*)carve((size_t)Etot * 4);                    // 3.4 MB
    int* row_start = (int*)carve((size_t)(N + 1) * 4);
    int* deg       = (int*)carve((size_t)N * 4);
    int* cursor    = (int*)carve((size_t)N * 4);
    int* bsum      = (int*)carve(1024 * 4);
    int* flags     = (int*)carve(256);

    hipMemsetAsync(deg, 0, (size_t)N * 4, stream);
    hipMemsetAsync(cursor, 0, (size_t)N * 4, stream);

    k_detect<<<1, 64, 0, stream>>>(edges_raw, flags);
    k_proj<<<(N + TM - 1) / TM, 256, 0, stream>>>(x, Wl, bl, Wr, br, xl, xr, N);
    k_hist<<<(Etot + 255) / 256, 256, 0, stream>>>(edges_raw, flags, deg, E,
                                                   Etot, N);
    const int NB = (N + 255) / 256;  // 196 <= 256: single-block scanB OK
    k_scanA<<<NB, 256, 0, stream>>>(deg, bsum, N);
    k_scanB<<<1, 256, 0, stream>>>(bsum, row_start, NB, Etot, N);
    k_scanC<<<NB, 256, 0, stream>>>(deg, bsum, row_start, N);
    k_scatter<<<(Etot + 255) / 256, 256, 0, stream>>>(edges_raw, flags,
                                                      row_start, cursor,
                                                      csr_src, E, Etot, N);
    k_aggregate<<<(N + 3) / 4, 256, 0, stream>>>(xl, xr, att, bias, row_start,
                                                 csr_src, (float*)d_out, N);
}

// Round 9
// 285.873 us; speedup vs baseline: 1.2299x; 1.0632x over previous
//
#include <hip/hip_runtime.h>

#define TM 16

// bf16 helpers (xl staged in bf16 to halve gather traffic)
__device__ __forceinline__ float u2f_lo(unsigned u) {
    union { unsigned u; float f; } c;
    c.u = u << 16;
    return c.f;
}
__device__ __forceinline__ float u2f_hi(unsigned u) {
    union { unsigned u; float f; } c;
    c.u = u & 0xffff0000u;
    return c.f;
}
// fp32 -> bf16 (round to nearest even)
__device__ __forceinline__ unsigned short f2b(float f) {
    union { float f; unsigned u; } c;
    c.f = f;
    unsigned r = c.u + 0x7fffu + ((c.u >> 16) & 1u);
    return (unsigned short)(r >> 16);
}

// edge dtype: int64 iff the 16 sampled high words are all zero (uniform
// scalar loads, evaluated per-block -- removes the k_detect dispatch).
__device__ __forceinline__ int edges_are_i64(const unsigned int* raw) {
    int f = 1;
#pragma unroll
    for (int k = 0; k < 16; ++k) f = f && (raw[2 * k + 1] == 0u);
    return f;
}
__device__ __forceinline__ int edge_at(const unsigned int* raw, int f,
                                       size_t idx) {
    return f ? (int)raw[2 * idx] : (int)raw[idx];
}

// ---------------------------------------------------------------------------
// K1: xl = x@W_l+b_l (-> bf16), xr = x@W_r+b_r (-> fp32). (Nx64)@(64x256).
// 16 nodes per 256-thread block; x-tile in LDS; thread j owns column j.
// ---------------------------------------------------------------------------
__global__ __launch_bounds__(256) void k_proj(
    const float* __restrict__ x, const float* __restrict__ Wl,
    const float* __restrict__ bl, const float* __restrict__ Wr,
    const float* __restrict__ br, unsigned short* __restrict__ xl,
    float* __restrict__ xr, int N) {
    __shared__ float xs[64][TM + 4];
    const int tid = threadIdx.x;
    const int base = blockIdx.x * TM;
    for (int t = tid; t < TM * 64; t += 256) {
        int m = t >> 6, k = t & 63;
        int n = base + m;
        xs[k][m] = (n < N) ? x[(size_t)n * 64 + k] : 0.f;
    }
    __syncthreads();
    const int j = tid;  // output column 0..255
    float accl[TM], accr[TM];
    const float blj = bl[j], brj = br[j];
#pragma unroll
    for (int m = 0; m < TM; ++m) { accl[m] = blj; accr[m] = brj; }
    for (int k = 0; k < 64; ++k) {
        float wl = Wl[(size_t)k * 256 + j];
        float wr = Wr[(size_t)k * 256 + j];
        const float4* xrow = (const float4*)(&xs[k][0]);
#pragma unroll
        for (int mm = 0; mm < TM / 4; ++mm) {
            float4 xv = xrow[mm];
            accl[4 * mm + 0] = fmaf(xv.x, wl, accl[4 * mm + 0]);
            accl[4 * mm + 1] = fmaf(xv.y, wl, accl[4 * mm + 1]);
            accl[4 * mm + 2] = fmaf(xv.z, wl, accl[4 * mm + 2]);
            accl[4 * mm + 3] = fmaf(xv.w, wl, accl[4 * mm + 3]);
            accr[4 * mm + 0] = fmaf(xv.x, wr, accr[4 * mm + 0]);
            accr[4 * mm + 1] = fmaf(xv.y, wr, accr[4 * mm + 1]);
            accr[4 * mm + 2] = fmaf(xv.z, wr, accr[4 * mm + 2]);
            accr[4 * mm + 3] = fmaf(xv.w, wr, accr[4 * mm + 3]);
        }
    }
#pragma unroll
    for (int m = 0; m < TM; ++m) {
        int n = base + m;
        if (n < N) {
            xl[(size_t)n * 256 + j] = f2b(accl[m]);
            xr[(size_t)n * 256 + j] = accr[m];
        }
    }
}

// ---------------------------------------------------------------------------
// CSR build: histogram -> block sums -> fused (scan-of-sums + local scan)
// -> scatter
// ---------------------------------------------------------------------------
__global__ void k_hist(const unsigned int* __restrict__ raw,
                       int* __restrict__ deg, int E, int Etot, int N) {
    int e = blockIdx.x * 256 + threadIdx.x;
    if (e >= Etot) return;
    int f = edges_are_i64(raw);
    int d = (e < E) ? edge_at(raw, f, (size_t)E + e) : (e - E);
    if ((unsigned)d >= (unsigned)N) d = 0;  // defensive clamp
    atomicAdd(&deg[d], 1);
}

__global__ void k_scanA(const int* __restrict__ deg, int* __restrict__ bsum,
                        int N) {
    __shared__ int s[256];
    int t = threadIdx.x;
    int i = blockIdx.x * 256 + t;
    s[t] = (i < N) ? deg[i] : 0;
    __syncthreads();
    for (int d = 128; d > 0; d >>= 1) {
        if (t < d) s[t] += s[t + d];
        __syncthreads();
    }
    if (t == 0) bsum[blockIdx.x] = s[0];
}

// fused: each block computes its global offset (masked reduce over bsum,
// NB <= 256) then the exclusive scan of its own 256 deg entries.
__global__ void k_scanC(const int* __restrict__ deg,
                        const int* __restrict__ bsum,
                        int* __restrict__ row_start, int Etot, int N) {
    __shared__ int s[256];
    __shared__ int off_s;
    const int t = threadIdx.x;
    // phase 1: offset = sum(bsum[0..blockIdx-1])  (t < blockIdx => t < NB)
    s[t] = (t < blockIdx.x) ? bsum[t] : 0;
    __syncthreads();
    for (int d = 128; d > 0; d >>= 1) {
        if (t < d) s[t] += s[t + d];
        __syncthreads();
    }
    if (t == 0) off_s = s[0];
    __syncthreads();
    const int offset = off_s;
    __syncthreads();
    // phase 2: exclusive scan of this block's deg slice
    const int i = blockIdx.x * 256 + t;
    const int v = (i < N) ? deg[i] : 0;
    s[t] = v;
    __syncthreads();
    for (int d = 1; d < 256; d <<= 1) {
        int add = (t >= d) ? s[t - d] : 0;
        __syncthreads();
        s[t] += add;
        __syncthreads();
    }
    if (i < N) row_start[i] = s[t] - v + offset;
    if (blockIdx.x == gridDim.x - 1 && t == 0) row_start[N] = Etot;
}

__global__ void k_scatter(const unsigned int* __restrict__ raw,
                          const int* __restrict__ row_start,
                          int* __restrict__ cursor, int* __restrict__ csr_src,
                          int E, int Etot, int N) {
    int e = blockIdx.x * 256 + threadIdx.x;
    if (e >= Etot) return;
    int f = edges_are_i64(raw);
    int s, d;
    if (e < E) {
        s = edge_at(raw, f, (size_t)e);
        d = edge_at(raw, f, (size_t)E + e);
    } else {
        s = d = e - E;
    }
    if ((unsigned)s >= (unsigned)N) s = 0;  // defensive clamp
    if ((unsigned)d >= (unsigned)N) d = 0;
    int pos = atomicAdd(&cursor[d], 1);
    int slot = row_start[d] + pos;
    if ((unsigned)slot < (unsigned)Etot) csr_src[slot] = s;
    // positions are a permutation of [0,Etot): every slot written, value < N.
}

// ---------------------------------------------------------------------------
// K3: per-node softmax-aggregate. One wave per node.
// lane -> (head = lane>>4, quad = lane&15): lane owns 4 channels of one head.
// r8 profile: VALU-issue-bound (VALUBusy 84%, ~115 wave-inst/edge, hbm 30%).
// This version: group-of-4 unrolled ping-pong pipeline (static indices, no
// register-ring shifts); tail edges masked by zeroing w (wave-uniform).
// ---------------------------------------------------------------------------
__global__ __launch_bounds__(256) void k_aggregate(
    const unsigned short* __restrict__ xl, const float* __restrict__ xr,
    const float* __restrict__ att, const float* __restrict__ bias,
    const int* __restrict__ row_start, const int* __restrict__ csr_src,
    float* __restrict__ out, int N) {
    const int wave = threadIdx.x >> 6;
    const int lane = threadIdx.x & 63;
    const int i = blockIdx.x * 4 + wave;
    if (i >= N) return;
    const int q = lane & 15;
    const int off = (lane >> 4) * 64 + q * 4;  // element offset in 256-row

    const float4 xr4 = *(const float4*)(xr + (size_t)i * 256 + off);
    const float4 a4 = *(const float4*)(att + off);
    float4 acc = make_float4(0.f, 0.f, 0.f, 0.f);
    float den = 0.f;
    const int beg = row_start[i];
    const int end = row_start[i + 1];  // deg >= 1 (self loop)
    const int last = end - 1;
    const unsigned short* xlo = xl + off;  // lane-constant base

    constexpr int U = 4;
    uint2 cur[U];  // gathered rows for edges e .. e+U-1
    int sidx[U];   // csr values for edges e+U .. e+2U-1
#pragma unroll
    for (int k = 0; k < U; ++k) {
        int s = csr_src[min(beg + k, last)];
        cur[k] = *(const uint2*)(xlo + (size_t)s * 256);
    }
#pragma unroll
    for (int k = 0; k < U; ++k) sidx[k] = csr_src[min(beg + U + k, last)];

    for (int e = beg; e < end; e += U) {
        uint2 nxt[U];
        int nidx[U];
#pragma unroll
        for (int k = 0; k < U; ++k)
            nxt[k] = *(const uint2*)(xlo + (size_t)sidx[k] * 256);
#pragma unroll
        for (int k = 0; k < U; ++k)
            nidx[k] = csr_src[min(e + 2 * U + k, last)];
#pragma unroll
        for (int k = 0; k < U; ++k) {
            const uint2 cu = cur[k];
            float c0 = u2f_lo(cu.x), c1 = u2f_hi(cu.x);
            float c2 = u2f_lo(cu.y), c3 = u2f_hi(cu.y);
            float v0 = c0 + xr4.x, v1 = c1 + xr4.y;
            float v2 = c2 + xr4.z, v3 = c3 + xr4.w;
            // lrelu(v) = max(v, 0.2v)
            v0 = fmaxf(v0, 0.2f * v0);
            v1 = fmaxf(v1, 0.2f * v1);
            v2 = fmaxf(v2, 0.2f * v2);
            v3 = fmaxf(v3, 0.2f * v3);
            float t = a4.x * v0;
            t = fmaf(a4.y, v1, t);
            t = fmaf(a4.z, v2, t);
            t = fmaf(a4.w, v3, t);
            t += __shfl_xor(t, 1);
            t += __shfl_xor(t, 2);
            t += __shfl_xor(t, 4);
            t += __shfl_xor(t, 8);  // full 64-chan dot for this head
            float w = __expf(fminf(t, 60.f));
            w = (e + k <= last) ? w : 0.f;  // mask tail re-gathers
            den += w;
            acc.x = fmaf(w, c0, acc.x);
            acc.y = fmaf(w, c1, acc.y);
            acc.z = fmaf(w, c2, acc.z);
            acc.w = fmaf(w, c3, acc.w);
        }
#pragma unroll
        for (int k = 0; k < U; ++k) { cur[k] = nxt[k]; sidx[k] = nidx[k]; }
    }
    const float inv = 1.f / den;
    float r0 = acc.x * inv, r1 = acc.y * inv, r2 = acc.z * inv, r3 = acc.w * inv;
    // sum over the 4 heads (lanes q, q+16, q+32, q+48)
    r0 += __shfl_xor(r0, 16); r0 += __shfl_xor(r0, 32);
    r1 += __shfl_xor(r1, 16); r1 += __shfl_xor(r1, 32);
    r2 += __shfl_xor(r2, 16); r2 += __shfl_xor(r2, 32);
    r3 += __shfl_xor(r3, 16); r3 += __shfl_xor(r3, 32);
    if (lane < 16) {
        const float4 b4 = *(const float4*)(bias + q * 4);
        *(float4*)(out + (size_t)i * 64 + q * 4) =
            make_float4(b4.x + 0.25f * r0, b4.y + 0.25f * r1,
                        b4.z + 0.25f * r2, b4.w + 0.25f * r3);
    }
}

// ---------------------------------------------------------------------------
extern "C" void kernel_launch(void* const* d_in, const int* in_sizes, int n_in,
                              void* d_out, int out_size, void* d_ws,
                              size_t ws_size, hipStream_t stream) {
    const float* x    = (const float*)d_in[0];
    const float* Wl   = (const float*)d_in[1];
    const float* bl   = (const float*)d_in[2];
    const float* Wr   = (const float*)d_in[3];
    const float* br   = (const float*)d_in[4];
    const float* att  = (const float*)d_in[5];
    const float* bias = (const float*)d_in[6];
    const unsigned int* edges_raw = (const unsigned int*)d_in[7];

    const int N = in_sizes[0] / 64;
    const int E = in_sizes[7] / 2;
    const int Etot = E + N;

    // workspace layout (~81 MB; evidenced safe r2/r5/r7/r8)
    char* p = (char*)d_ws;
    size_t off = 0;
    auto carve = [&](size_t bytes) -> char* {
        char* r = p + off;
        off = (off + bytes + 255) & ~(size_t)255;
        return r;
    };
    unsigned short* xl = (unsigned short*)carve((size_t)N * 256 * 2);  // 25.6 MB
    float* xr      = (float*)carve((size_t)N * 256 * 4);               // 51.2 MB
    int* csr_src   = (int*)carve((size_t)Etot * 4);                    // 3.4 MB
    int* row_start = (int*)carve((size_t)(N + 1) * 4);
    int* degcur    = (int*)carve((size_t)2 * N * 4);  // deg | cursor, one memset
    int* deg       = degcur;
    int* cursor    = degcur + N;
    int* bsum      = (int*)carve(1024 * 4);

    hipMemsetAsync(degcur, 0, (size_t)2 * N * 4, stream);

    k_proj<<<(N + TM - 1) / TM, 256, 0, stream>>>(x, Wl, bl, Wr, br, xl, xr, N);
    k_hist<<<(Etot + 255) / 256, 256, 0, stream>>>(edges_raw, deg, E, Etot, N);
    const int NB = (N + 255) / 256;  // 196 <= 256: bsum prefix fits one block
    k_scanA<<<NB, 256, 0, stream>>>(deg, bsum, N);
    k_scanC<<<NB, 256, 0, stream>>>(deg, bsum, row_start, Etot, N);
    k_scatter<<<(Etot + 255) / 256, 256, 0, stream>>>(edges_raw, row_start,
                                                      cursor, csr_src, E, Etot,
                                                      N);
    k_aggregate<<<(N + 3) / 4, 256, 0, stream>>>(xl, xr, att, bias, row_start,
                                                 csr_src, (float*)d_out, N);
}